// Round 5
// baseline (143.574 us; speedup 1.0000x reference)
//
#include <hip/hip_runtime.h>
#include <stdint.h>

// Problem constants (fixed by reference)
#define B_  32
#define N_  128
#define NIN 16
#define K_  4
#define E_  (N_*(N_-1))   // 16256

typedef float    f4 __attribute__((ext_vector_type(4)));
typedef _Float16 h8 __attribute__((ext_vector_type(8)));   // 8 fp16 = 4 VGPRs
typedef _Float16 h4 __attribute__((ext_vector_type(4)));   // 4 fp16 = 2 VGPRs

// ---------------------------------------------------------------------------
// Prep (single launch, block ranges):
//   [0,1024):      S/R per-node layer-1 halves (fp16), 4 outputs/thread, f4 loads
//   [1024,1088):   W2 -> fp16 MFMA B-operand fragments (edge kernel)
//   [1088,1132):   Wo1/Wo2/Wo3 -> fp16 MFMA B-operand fragments (node kernel)
//                  wn frag f: 0..11 = Wo1[ks(3)][nt(4)] (K padded 80->96, zero),
//                  12..19 = Wo2[ks(2)][nt(4)], 20..21 = Wo3[ks(2)] (N=16)
// ---------------------------------------------------------------------------
__global__ __launch_bounds__(256) void prep(
    const float* __restrict__ inp, const float* __restrict__ W1,
    const float* __restrict__ b1,  const float* __restrict__ W2,
    const float* __restrict__ Wo1, const float* __restrict__ Wo2,
    const float* __restrict__ Wo3,
    _Float16* __restrict__ Sh, _Float16* __restrict__ Rh,
    _Float16* __restrict__ w2h, _Float16* __restrict__ wn)
{
    const int bid = blockIdx.x;
    const int tid = threadIdx.x;
    if (bid < 1024) {
        // 4 consecutive c per thread; S = x@W1[:16], R = x@W1[16:] + b1
        int gid = bid*256 + tid;            // c4:4 | n:7 | b:5 | k:2
        int c0 = (gid & 15)*4;
        int n  = (gid >> 4) & 127;
        int b  = (gid >> 11) & 31;
        int k  = gid >> 16;
        f4 s = {0.f,0.f,0.f,0.f};
        f4 r = *(const f4*)(b1 + k*64 + c0);
        const float* xp  = inp + (b*NIN)*N_ + n;          // inputs[b][f][n]
        const f4* w1s = (const f4*)(W1 + (k*32)*64 + c0);      // stride 16 f4
        const f4* w1r = (const f4*)(W1 + (k*32 + 16)*64 + c0);
        #pragma unroll
        for (int f = 0; f < 16; ++f) {
            float xv = xp[f*N_];
            s += xv * w1s[f*16];
            r += xv * w1r[f*16];
        }
        int base = ((k*B_ + b)*N_ + n)*64 + c0;
        h4 sh, rh;
        #pragma unroll
        for (int u = 0; u < 4; ++u) { sh[u] = (_Float16)s[u]; rh[u] = (_Float16)r[u]; }
        *(h4*)(Sh + base) = sh;
        *(h4*)(Rh + base) = rh;
    } else if (bid < 1088) {
        // edge B-frag: lane holds B[kk=q*8+i][n=nt*16+col]
        int t = (bid - 1024)*256 + tid;     // i:3 | lane:6 | nt:2 | ks:1 | k:2
        int i    = t & 7;
        int lane = (t >> 3) & 63;
        int nt   = (t >> 9) & 3;
        int ks   = (t >> 11) & 1;
        int k    = t >> 12;
        int c = ks*32 + (lane >> 4)*8 + i;
        int o = nt*16 + (lane & 15);
        w2h[t] = (_Float16)W2[(k*64 + c)*64 + o];
    } else {
        // node-MLP B-frags (11264 = 44*256 exactly)
        int t = (bid - 1088)*256 + tid;     // j:3 | lane:6 | f:5
        int j    = t & 7;
        int lane = (t >> 3) & 63;
        int f    = t >> 9;                  // 0..21
        int col = lane & 15, q = lane >> 4, row = q*8 + j;
        float v;
        if (f < 12) {
            int ks = f >> 2, nt = f & 3, i = ks*32 + row;
            v = (i < 80) ? Wo1[i*64 + nt*16 + col] : 0.f;
        } else if (f < 20) {
            int g = f - 12, ks = g >> 2, nt = g & 3, i = ks*32 + row;
            v = Wo2[i*64 + nt*16 + col];
        } else {
            int ks = f - 20, i = ks*32 + row;
            v = Wo3[i*16 + col];
        }
        wn[t] = (_Float16)v;
    }
}

// ---------------------------------------------------------------------------
// Edge MLP (fp16 MFMA) + receiver aggregation.
// Block = (k, b, quarter-of-receivers): 512 blocks x 512 threads (8 waves).
// S[k][b] staged in LDS (XOR-swizzled 16B chunks). rel_types read DIRECTLY
// from rt with quad-broadcast predicated loads (s==r masked -> no load).
// ---------------------------------------------------------------------------
__global__ __launch_bounds__(512) void edge_mfma(
    const _Float16* __restrict__ Sh, const _Float16* __restrict__ Rh,
    const _Float16* __restrict__ w2h, const float* __restrict__ rt,
    const float* __restrict__ b2, float* __restrict__ aggK)
{
    __shared__ _Float16 Ssw[N_*64];     // 16 KB, XOR-swizzled 16B chunks

    const int tid  = threadIdx.x;
    const int wave = tid >> 6;
    const int lane = tid & 63;
    const int col  = lane & 15;
    const int q    = lane >> 4;
    const int bid  = blockIdx.x;        // (k*32 + b)*4 + rt4
    const int rt4  = bid & 3;
    const int b    = (bid >> 2) & 31;
    const int k    = bid >> 7;
    const int kb   = k*B_ + b;

    // ---- stage S[k][b] into LDS, chunk p = s*8 + (c8 ^ (s&7)) ----
    const _Float16* Sg = Sh + (size_t)kb*(N_*64);
    #pragma unroll
    for (int rnd = 0; rnd < 2; ++rnd) {
        int p  = rnd*512 + tid;
        int s  = p >> 3;
        int c8 = (p & 7) ^ (s & 7);
        h8 v = *(const h8*)(Sg + (s*8 + c8)*8);
        *(h8*)(Ssw + p*8) = v;
    }

    // W2 B-operand fragments
    const h8* w2v = (const h8*)w2h;
    h8 w2f[2][4];
    #pragma unroll
    for (int ks = 0; ks < 2; ++ks)
        #pragma unroll
        for (int nt = 0; nt < 4; ++nt)
            w2f[ks][nt] = w2v[((k*2 + ks)*4 + nt)*64 + lane];

    // b2 folded into accumulator init (C col = lane&15 for all 4 regs)
    f4 b2i[4];
    #pragma unroll
    for (int nt = 0; nt < 4; ++nt) {
        float v = b2[k*64 + nt*16 + col];
        b2i[nt][0] = v; b2i[nt][1] = v; b2i[nt][2] = v; b2i[nt][3] = v;
    }

    __syncthreads();

    const h8* Rv = (const h8*)Rh;
    const h8 zero8 = {0,0,0,0,0,0,0,0};

    #pragma unroll 1
    for (int rg = 0; rg < 4; ++rg) {
        const int r = rt4*32 + wave*4 + rg;
        h8 rf0 = Rv[(kb*N_ + r)*8 + q];
        h8 rf1 = Rv[(kb*N_ + r)*8 + 4 + q];
        const float* rtb = rt + ((size_t)(b*E_ + r*127))*4 + k;

        float aggacc[4] = {0.f, 0.f, 0.f, 0.f};
        #pragma unroll
        for (int mt = 0; mt < 8; ++mt) {
            // rel_types weights for this tile's rows (quad-broadcast loads)
            float rtv[4];
            #pragma unroll
            for (int i = 0; i < 4; ++i) {
                int sdx = mt*16 + q*4 + i;
                float v = 0.f;
                if (sdx != r) v = rtb[(sdx - (sdx > r ? 1 : 0))*4];
                rtv[i] = v;
            }
            int s  = mt*16 + col;                   // A row = lane&15
            int x0 = (s*8 + (q       ^ (s & 7)))*8;
            int x1 = (s*8 + ((4 + q) ^ (s & 7)))*8;
            h8 a0 = *(const h8*)(Ssw + x0);
            h8 a1 = *(const h8*)(Ssw + x1);
            a0 = __builtin_elementwise_max(a0 + rf0, zero8);  // h1 = relu(S+R)
            a1 = __builtin_elementwise_max(a1 + rf1, zero8);

            #pragma unroll
            for (int nt = 0; nt < 4; ++nt) {
                f4 acc = __builtin_amdgcn_mfma_f32_16x16x32_f16(a0, w2f[0][nt], b2i[nt], 0, 0, 0);
                acc     = __builtin_amdgcn_mfma_f32_16x16x32_f16(a1, w2f[1][nt], acc,    0, 0, 0);
                // C/D: col = lane&15, row = q*4 + reg
                #pragma unroll
                for (int i = 0; i < 4; ++i)
                    aggacc[nt] += rtv[i] * fmaxf(acc[i], 0.f);
            }
        }
        // rows live in quads -> cross-quad reduce, 16 lanes store
        #pragma unroll
        for (int nt = 0; nt < 4; ++nt) {
            float v = aggacc[nt];
            v += __shfl_xor(v, 16, 64);
            v += __shfl_xor(v, 32, 64);
            if (lane < 16) aggK[((size_t)kb*N_ + r)*64 + nt*16 + lane] = v;
        }
    }
}

// ---------------------------------------------------------------------------
// Node MLP via MFMA. Block = (b, half-of-r): 64 blocks x 256 thr (4 waves).
// aug[64 nodes][96 pad] fp16 in LDS (XOR-swizzled); wave mt owns nodes
// mt*16..+15; 3 GEMM layers, inter-layer h in wave-private LDS rows (one
// barrier total). B-frags prepacked in wn.
// ---------------------------------------------------------------------------
__global__ __launch_bounds__(256) void node_mfma(
    const float* __restrict__ aggK, const float* __restrict__ inp,
    const _Float16* __restrict__ wn,
    const float* __restrict__ bo1, const float* __restrict__ bo2,
    const float* __restrict__ bo3, float* __restrict__ out)
{
    __shared__ _Float16 augH[64*128];   // 64 rows x 16 chunks x 8 fp16 = 16 KB
    __shared__ _Float16 h12[64*64];     // 64 rows x 8 chunks x 8 fp16 = 8 KB

    const int tid = threadIdx.x;
    const int b   = blockIdx.x >> 1;
    const int r0  = (blockIdx.x & 1)*64;

    // ---- build aug[node][96]: [x(16) | sum_k aggK (64) | zeros(16)] ----
    {
        const int nl = tid >> 2, c4 = tid & 3;      // node-local, quarter
        const int r  = r0 + nl;
        float xv[4];
        #pragma unroll
        for (int u = 0; u < 4; ++u)
            xv[u] = inp[(b*NIN + c4*4 + u)*N_ + r];
        f4 av[4];
        #pragma unroll
        for (int w = 0; w < 4; ++w) {
            int c = w*16 + c4*4;
            f4 a = {0.f,0.f,0.f,0.f};
            #pragma unroll
            for (int k = 0; k < 4; ++k)
                a += *(const f4*)(aggK + (((size_t)k*B_ + b)*N_ + r)*64 + c);
            av[w] = a;
        }
        #pragma unroll
        for (int u = 0; u < 4; ++u) {
            int i = c4*4 + u;
            augH[nl*128 + (((i>>3) ^ (nl&15))<<3) + (i&7)] = (_Float16)xv[u];
        }
        #pragma unroll
        for (int w = 0; w < 4; ++w)
            #pragma unroll
            for (int u = 0; u < 4; ++u) {
                int i = 16 + w*16 + c4*4 + u;
                augH[nl*128 + (((i>>3) ^ (nl&15))<<3) + (i&7)] = (_Float16)av[w][u];
            }
        if (c4 < 2)
            #pragma unroll
            for (int u = 0; u < 8; ++u) {
                int i = 80 + c4*8 + u;
                augH[nl*128 + (((i>>3) ^ (nl&15))<<3) + (i&7)] = (_Float16)0.f;
            }
    }
    __syncthreads();

    // ---- GEMM chain: wave mt -> nodes mt*16..+15 ----
    const int mt  = tid >> 6, lane = tid & 63;
    const int col = lane & 15, q = lane >> 4;
    const h8* wv   = (const h8*)wn;
    const h8* augV = (const h8*)augH;
    const h8* hv   = (const h8*)h12;
    const int nl   = mt*16 + col;       // A row (node); nl&15 == col

    // layer 1: [96] -> [64], relu
    f4 acc[4];
    #pragma unroll
    for (int nt = 0; nt < 4; ++nt) {
        float v = bo1[nt*16 + col];
        acc[nt][0] = v; acc[nt][1] = v; acc[nt][2] = v; acc[nt][3] = v;
    }
    #pragma unroll
    for (int ks = 0; ks < 3; ++ks) {
        h8 af = augV[nl*16 + ((ks*4 + q) ^ col)];
        #pragma unroll
        for (int nt = 0; nt < 4; ++nt)
            acc[nt] = __builtin_amdgcn_mfma_f32_16x16x32_f16(af, wv[(ks*4 + nt)*64 + lane], acc[nt], 0, 0, 0);
    }
    #pragma unroll
    for (int nt = 0; nt < 4; ++nt)
        #pragma unroll
        for (int i = 0; i < 4; ++i) {
            int n2 = mt*16 + q*4 + i, o = nt*16 + col;
            h12[n2*64 + (((o>>3) ^ (n2&7))<<3) + (o&7)] = (_Float16)fmaxf(acc[nt][i], 0.f);
        }

    // layer 2: [64] -> [64], relu (wave-private rows; in-order LDS, no barrier)
    f4 acc2[4];
    #pragma unroll
    for (int nt = 0; nt < 4; ++nt) {
        float v = bo2[nt*16 + col];
        acc2[nt][0] = v; acc2[nt][1] = v; acc2[nt][2] = v; acc2[nt][3] = v;
    }
    #pragma unroll
    for (int ks = 0; ks < 2; ++ks) {
        h8 af = hv[nl*8 + ((ks*4 + q) ^ (col & 7))];
        #pragma unroll
        for (int nt = 0; nt < 4; ++nt)
            acc2[nt] = __builtin_amdgcn_mfma_f32_16x16x32_f16(af, wv[(12 + ks*4 + nt)*64 + lane], acc2[nt], 0, 0, 0);
    }
    #pragma unroll
    for (int nt = 0; nt < 4; ++nt)
        #pragma unroll
        for (int i = 0; i < 4; ++i) {
            int n2 = mt*16 + q*4 + i, o = nt*16 + col;
            h12[n2*64 + (((o>>3) ^ (n2&7))<<3) + (o&7)] = (_Float16)fmaxf(acc2[nt][i], 0.f);
        }

    // layer 3: [64] -> [16], no relu
    f4 acc3;
    {
        float v = bo3[col];
        acc3[0] = v; acc3[1] = v; acc3[2] = v; acc3[3] = v;
    }
    #pragma unroll
    for (int ks = 0; ks < 2; ++ks) {
        h8 af = hv[nl*8 + ((ks*4 + q) ^ (col & 7))];
        acc3 = __builtin_amdgcn_mfma_f32_16x16x32_f16(af, wv[(20 + ks)*64 + lane], acc3, 0, 0, 0);
    }
    #pragma unroll
    for (int i = 0; i < 4; ++i) {
        int r = r0 + mt*16 + q*4 + i;
        out[(b*NIN + col)*N_ + r] = acc3[i];   // pred transposed: [B, n_out, N]
    }
}

// ---------------------------------------------------------------------------
extern "C" void kernel_launch(void* const* d_in, const int* in_sizes, int n_in,
                              void* d_out, int out_size, void* d_ws, size_t ws_size,
                              hipStream_t stream)
{
    const float* inp = (const float*)d_in[0];
    // d_in[1] = rel_rec, d_in[2] = rel_send: one-hot, decoded analytically, unused
    const float* rt  = (const float*)d_in[3];
    const float* W1  = (const float*)d_in[4];
    const float* b1  = (const float*)d_in[5];
    const float* W2  = (const float*)d_in[6];
    const float* b2  = (const float*)d_in[7];
    const float* Wo1 = (const float*)d_in[8];
    const float* bo1 = (const float*)d_in[9];
    const float* Wo2 = (const float*)d_in[10];
    const float* bo2 = (const float*)d_in[11];
    const float* Wo3 = (const float*)d_in[12];
    const float* bo3 = (const float*)d_in[13];

    // ws: Sh 2MB | Rh 2MB | w2h 32KB | wn 22KB | aggK 4MB  (~8.3MB)
    _Float16* Sh   = (_Float16*)d_ws;
    _Float16* Rh   = Sh + (1u << 20);
    _Float16* w2h  = Rh + (1u << 20);
    _Float16* wn   = w2h + 16384;
    float*    aggK = (float*)(wn + 11264);

    hipLaunchKernelGGL(prep, dim3(1132), dim3(256), 0, stream,
                       inp, W1, b1, W2, Wo1, Wo2, Wo3, Sh, Rh, w2h, wn);
    hipLaunchKernelGGL(edge_mfma, dim3(512), dim3(512), 0, stream,
                       Sh, Rh, w2h, rt, b2, aggK);
    hipLaunchKernelGGL(node_mfma, dim3(64), dim3(256), 0, stream,
                       aggK, inp, wn, bo1, bo2, bo3, (float*)d_out);
}

// Round 6
// 137.700 us; speedup vs baseline: 1.0427x; 1.0427x over previous
//
#include <hip/hip_runtime.h>
#include <stdint.h>

// Problem constants (fixed by reference)
#define B_  32
#define N_  128
#define NIN 16
#define K_  4
#define E_  (N_*(N_-1))   // 16256

typedef float    f4 __attribute__((ext_vector_type(4)));
typedef _Float16 h8 __attribute__((ext_vector_type(8)));   // 8 fp16 = 4 VGPRs
typedef _Float16 h4 __attribute__((ext_vector_type(4)));   // 4 fp16 = 2 VGPRs

// ---------------------------------------------------------------------------
// Prep (single launch, block ranges):
//   [0,1024):      S/R per-node layer-1 halves (fp16), 4 outputs/thread
//   [1024,1088):   W2 -> fp16 MFMA B-operand fragments (edge kernel)
//   [1088,1132):   Wo1/Wo2/Wo3 -> fp16 MFMA B-operand fragments (node kernel)
//   [1132,1644):   rel_types -> rtn[k][b][r][s] fp16, diagonal zeroed
//                  (sender-indexed: s = j + (j>=r)); coalesced float4 reads
// ---------------------------------------------------------------------------
__global__ __launch_bounds__(256) void prep(
    const float* __restrict__ inp, const float* __restrict__ W1,
    const float* __restrict__ b1,  const float* __restrict__ W2,
    const float* __restrict__ Wo1, const float* __restrict__ Wo2,
    const float* __restrict__ Wo3, const float* __restrict__ rt,
    _Float16* __restrict__ Sh, _Float16* __restrict__ Rh,
    _Float16* __restrict__ w2h, _Float16* __restrict__ wn,
    _Float16* __restrict__ rtn)
{
    const int bid = blockIdx.x;
    const int tid = threadIdx.x;
    if (bid < 1024) {
        // 4 consecutive c per thread; S = x@W1[:16], R = x@W1[16:] + b1
        int gid = bid*256 + tid;            // c4:4 | n:7 | b:5 | k:2
        int c0 = (gid & 15)*4;
        int n  = (gid >> 4) & 127;
        int b  = (gid >> 11) & 31;
        int k  = gid >> 16;
        f4 s = {0.f,0.f,0.f,0.f};
        f4 r = *(const f4*)(b1 + k*64 + c0);
        const float* xp  = inp + (b*NIN)*N_ + n;          // inputs[b][f][n]
        const f4* w1s = (const f4*)(W1 + (k*32)*64 + c0);      // stride 16 f4
        const f4* w1r = (const f4*)(W1 + (k*32 + 16)*64 + c0);
        #pragma unroll
        for (int f = 0; f < 16; ++f) {
            float xv = xp[f*N_];
            s += xv * w1s[f*16];
            r += xv * w1r[f*16];
        }
        int base = ((k*B_ + b)*N_ + n)*64 + c0;
        h4 sh, rh;
        #pragma unroll
        for (int u = 0; u < 4; ++u) { sh[u] = (_Float16)s[u]; rh[u] = (_Float16)r[u]; }
        *(h4*)(Sh + base) = sh;
        *(h4*)(Rh + base) = rh;
    } else if (bid < 1088) {
        // edge B-frag: lane holds B[kk=q*8+i][n=nt*16+col]
        int t = (bid - 1024)*256 + tid;     // i:3 | lane:6 | nt:2 | ks:1 | k:2
        int i    = t & 7;
        int lane = (t >> 3) & 63;
        int nt   = (t >> 9) & 3;
        int ks   = (t >> 11) & 1;
        int k    = t >> 12;
        int c = ks*32 + (lane >> 4)*8 + i;
        int o = nt*16 + (lane & 15);
        w2h[t] = (_Float16)W2[(k*64 + c)*64 + o];
    } else if (bid < 1132) {
        // node-MLP B-frags (11264 = 44*256 exactly)
        int t = (bid - 1088)*256 + tid;     // j:3 | lane:6 | f:5
        int j    = t & 7;
        int lane = (t >> 3) & 63;
        int f    = t >> 9;                  // 0..21
        int col = lane & 15, q = lane >> 4, row = q*8 + j;
        float v;
        if (f < 12) {
            int ks = f >> 2, nt = f & 3, i = ks*32 + row;
            v = (i < 80) ? Wo1[i*64 + nt*16 + col] : 0.f;
        } else if (f < 20) {
            int g = f - 12, ks = g >> 2, nt = g & 3, i = ks*32 + row;
            v = Wo2[i*64 + nt*16 + col];
        } else {
            int ks = f - 20, i = ks*32 + row;
            v = Wo3[i*16 + col];
        }
        wn[t] = (_Float16)v;
    } else {
        // rtn[k][b][r][s]: sender-indexed edge weight, 0 on diagonal.
        // thread <-> (b, r, jg); reads float4 over k (fully coalesced).
        int t = (bid - 1132)*256 + tid;     // jg:5 | r:7 | b:5
        int jg = t & 31;
        int r  = (t >> 5) & 127;
        int b  = t >> 12;
        const f4* rt4p = (const f4*)(rt + (size_t)(b*E_ + r*127)*4);
        #pragma unroll
        for (int u = 0; u < 4; ++u) {
            int j = jg*4 + u;
            if (j < 127) {
                f4 v = rt4p[j];
                int s = j + (j >= r ? 1 : 0);
                #pragma unroll
                for (int k = 0; k < 4; ++k)
                    rtn[((k*B_ + b)*N_ + r)*N_ + s] = (_Float16)v[k];
            } else {
                #pragma unroll
                for (int k = 0; k < 4; ++k)      // zero the diagonal
                    rtn[((k*B_ + b)*N_ + r)*N_ + r] = (_Float16)0.f;
            }
        }
    }
}

// ---------------------------------------------------------------------------
// Edge MLP (fp16 MFMA) + receiver aggregation.
// Block = (k, b, quarter-of-receivers): 512 blocks x 512 threads (8 waves).
// ALL block data staged to LDS in one coalesced burst (S 16KB swizzled,
// R rows 4KB, rtn rows 8KB) -> compute phase has ZERO global loads.
// Register budget ~103 < 112 (no spill, 4 waves/SIMD).
// ---------------------------------------------------------------------------
__global__ __launch_bounds__(512) void edge_mfma(
    const _Float16* __restrict__ Sh, const _Float16* __restrict__ Rh,
    const _Float16* __restrict__ w2h, const _Float16* __restrict__ rtn,
    const float* __restrict__ b2, float* __restrict__ aggK)
{
    __shared__ _Float16 Ssw[N_*64];     // 16 KB, XOR-swizzled 16B chunks
    __shared__ _Float16 Rl[32*64];      // 4 KB: R rows for 32 receivers
    __shared__ _Float16 Rt[32*128];     // 8 KB: rtn rows for 32 receivers

    const int tid  = threadIdx.x;
    const int wave = tid >> 6;
    const int lane = tid & 63;
    const int col  = lane & 15;
    const int q    = lane >> 4;
    const int bid  = blockIdx.x;        // (k*32 + b)*4 + rt4
    const int rt4  = bid & 3;
    const int b    = (bid >> 2) & 31;
    const int k    = bid >> 7;
    const int kb   = k*B_ + b;
    const int r0   = rt4*32;

    // ---- coalesced staging burst (all loads issue back-to-back) ----
    const _Float16* Sg = Sh + (size_t)kb*(N_*64);
    #pragma unroll
    for (int rnd = 0; rnd < 2; ++rnd) {
        int p  = rnd*512 + tid;
        int s  = p >> 3;
        int c8 = (p & 7) ^ (s & 7);     // swizzle: chunk p=s*8+(c8^(s&7))
        *(h8*)(Ssw + p*8) = *(const h8*)(Sg + (s*8 + c8)*8);
    }
    if (tid < 256)                      // R rows r0..r0+31 (2048 fp16)
        *(h8*)(Rl + tid*8) = *(const h8*)(Rh + ((size_t)kb*N_ + r0)*64 + tid*8);
    *(h8*)(Rt + tid*8) =                // rtn rows (4096 fp16)
        *(const h8*)(rtn + ((size_t)kb*N_ + r0)*N_ + tid*8);

    // W2 B-operand fragments (global, L2-broadcast; independent of LDS)
    const h8* w2v = (const h8*)w2h;
    h8 w2f[2][4];
    #pragma unroll
    for (int ks = 0; ks < 2; ++ks)
        #pragma unroll
        for (int nt = 0; nt < 4; ++nt)
            w2f[ks][nt] = w2v[((k*2 + ks)*4 + nt)*64 + lane];

    // b2 folded into accumulator init (C col = lane&15 for all 4 regs)
    f4 b2i[4];
    #pragma unroll
    for (int nt = 0; nt < 4; ++nt) {
        float v = b2[k*64 + nt*16 + col];
        b2i[nt][0] = v; b2i[nt][1] = v; b2i[nt][2] = v; b2i[nt][3] = v;
    }

    __syncthreads();

    const h8 zero8 = {0,0,0,0,0,0,0,0};

    #pragma unroll 1
    for (int rg = 0; rg < 4; ++rg) {
        const int rl = wave*4 + rg;     // receiver-local index
        const int r  = r0 + rl;
        h8 rf0 = *(const h8*)(Rl + rl*64 + q*8);
        h8 rf1 = *(const h8*)(Rl + rl*64 + (4 + q)*8);
        h4 rth[8];
        #pragma unroll
        for (int mt = 0; mt < 8; ++mt)
            rth[mt] = *(const h4*)(Rt + rl*128 + mt*16 + q*4);

        float aggacc[4] = {0.f, 0.f, 0.f, 0.f};
        #pragma unroll
        for (int mt = 0; mt < 8; ++mt) {
            int s  = mt*16 + col;                   // A row = lane&15
            int x0 = (s*8 + (q       ^ (s & 7)))*8;
            int x1 = (s*8 + ((4 + q) ^ (s & 7)))*8;
            h8 a0 = *(const h8*)(Ssw + x0);
            h8 a1 = *(const h8*)(Ssw + x1);
            a0 = __builtin_elementwise_max(a0 + rf0, zero8);  // h1 = relu(S+R)
            a1 = __builtin_elementwise_max(a1 + rf1, zero8);
            float rtv[4];
            #pragma unroll
            for (int i = 0; i < 4; ++i) rtv[i] = (float)rth[mt][i];

            #pragma unroll
            for (int nt = 0; nt < 4; ++nt) {
                f4 acc = __builtin_amdgcn_mfma_f32_16x16x32_f16(a0, w2f[0][nt], b2i[nt], 0, 0, 0);
                acc     = __builtin_amdgcn_mfma_f32_16x16x32_f16(a1, w2f[1][nt], acc,    0, 0, 0);
                // C/D: col = lane&15, row = q*4 + reg
                #pragma unroll
                for (int i = 0; i < 4; ++i)
                    aggacc[nt] += rtv[i] * fmaxf(acc[i], 0.f);
            }
        }
        // rows live in quads -> cross-quad reduce, 16 lanes store
        #pragma unroll
        for (int nt = 0; nt < 4; ++nt) {
            float v = aggacc[nt];
            v += __shfl_xor(v, 16, 64);
            v += __shfl_xor(v, 32, 64);
            if (lane < 16) aggK[((size_t)kb*N_ + r)*64 + nt*16 + lane] = v;
        }
    }
}

// ---------------------------------------------------------------------------
// Node MLP via MFMA. Block = (b, half-of-r): 64 blocks x 256 thr (4 waves).
// aug[64 nodes][96 pad] fp16 in LDS (XOR-swizzled); wave mt owns nodes
// mt*16..+15; 3 GEMM layers, inter-layer h in wave-private LDS rows.
// ---------------------------------------------------------------------------
__global__ __launch_bounds__(256) void node_mfma(
    const float* __restrict__ aggK, const float* __restrict__ inp,
    const _Float16* __restrict__ wn,
    const float* __restrict__ bo1, const float* __restrict__ bo2,
    const float* __restrict__ bo3, float* __restrict__ out)
{
    __shared__ _Float16 augH[64*128];   // 16 KB
    __shared__ _Float16 h12[64*64];     // 8 KB

    const int tid = threadIdx.x;
    const int b   = blockIdx.x >> 1;
    const int r0  = (blockIdx.x & 1)*64;

    // ---- build aug[node][96]: [x(16) | sum_k aggK (64) | zeros(16)] ----
    {
        const int nl = tid >> 2, c4 = tid & 3;      // node-local, quarter
        const int r  = r0 + nl;
        float xv[4];
        #pragma unroll
        for (int u = 0; u < 4; ++u)
            xv[u] = inp[(b*NIN + c4*4 + u)*N_ + r];
        f4 av[4];
        #pragma unroll
        for (int w = 0; w < 4; ++w) {
            int c = w*16 + c4*4;
            f4 a = {0.f,0.f,0.f,0.f};
            #pragma unroll
            for (int k = 0; k < 4; ++k)
                a += *(const f4*)(aggK + (((size_t)k*B_ + b)*N_ + r)*64 + c);
            av[w] = a;
        }
        #pragma unroll
        for (int u = 0; u < 4; ++u) {
            int i = c4*4 + u;
            augH[nl*128 + (((i>>3) ^ (nl&15))<<3) + (i&7)] = (_Float16)xv[u];
        }
        #pragma unroll
        for (int w = 0; w < 4; ++w)
            #pragma unroll
            for (int u = 0; u < 4; ++u) {
                int i = 16 + w*16 + c4*4 + u;
                augH[nl*128 + (((i>>3) ^ (nl&15))<<3) + (i&7)] = (_Float16)av[w][u];
            }
        if (c4 < 2)
            #pragma unroll
            for (int u = 0; u < 8; ++u) {
                int i = 80 + c4*8 + u;
                augH[nl*128 + (((i>>3) ^ (nl&15))<<3) + (i&7)] = (_Float16)0.f;
            }
    }
    __syncthreads();

    // ---- GEMM chain: wave mt -> nodes mt*16..+15 ----
    const int mt  = tid >> 6, lane = tid & 63;
    const int col = lane & 15, q = lane >> 4;
    const h8* wv   = (const h8*)wn;
    const h8* augV = (const h8*)augH;
    const h8* hv   = (const h8*)h12;
    const int nl   = mt*16 + col;       // A row (node); nl&15 == col

    // layer 1: [96] -> [64], relu
    f4 acc[4];
    #pragma unroll
    for (int nt = 0; nt < 4; ++nt) {
        float v = bo1[nt*16 + col];
        acc[nt][0] = v; acc[nt][1] = v; acc[nt][2] = v; acc[nt][3] = v;
    }
    #pragma unroll
    for (int ks = 0; ks < 3; ++ks) {
        h8 af = augV[nl*16 + ((ks*4 + q) ^ col)];
        #pragma unroll
        for (int nt = 0; nt < 4; ++nt)
            acc[nt] = __builtin_amdgcn_mfma_f32_16x16x32_f16(af, wv[(ks*4 + nt)*64 + lane], acc[nt], 0, 0, 0);
    }
    #pragma unroll
    for (int nt = 0; nt < 4; ++nt)
        #pragma unroll
        for (int i = 0; i < 4; ++i) {
            int n2 = mt*16 + q*4 + i, o = nt*16 + col;
            h12[n2*64 + (((o>>3) ^ (n2&7))<<3) + (o&7)] = (_Float16)fmaxf(acc[nt][i], 0.f);
        }

    // layer 2: [64] -> [64], relu (wave-private rows; in-order LDS)
    f4 acc2[4];
    #pragma unroll
    for (int nt = 0; nt < 4; ++nt) {
        float v = bo2[nt*16 + col];
        acc2[nt][0] = v; acc2[nt][1] = v; acc2[nt][2] = v; acc2[nt][3] = v;
    }
    #pragma unroll
    for (int ks = 0; ks < 2; ++ks) {
        h8 af = hv[nl*8 + ((ks*4 + q) ^ (col & 7))];
        #pragma unroll
        for (int nt = 0; nt < 4; ++nt)
            acc2[nt] = __builtin_amdgcn_mfma_f32_16x16x32_f16(af, wv[(12 + ks*4 + nt)*64 + lane], acc2[nt], 0, 0, 0);
    }
    #pragma unroll
    for (int nt = 0; nt < 4; ++nt)
        #pragma unroll
        for (int i = 0; i < 4; ++i) {
            int n2 = mt*16 + q*4 + i, o = nt*16 + col;
            h12[n2*64 + (((o>>3) ^ (n2&7))<<3) + (o&7)] = (_Float16)fmaxf(acc2[nt][i], 0.f);
        }

    // layer 3: [64] -> [16], no relu
    f4 acc3;
    {
        float v = bo3[col];
        acc3[0] = v; acc3[1] = v; acc3[2] = v; acc3[3] = v;
    }
    #pragma unroll
    for (int ks = 0; ks < 2; ++ks) {
        h8 af = hv[nl*8 + ((ks*4 + q) ^ (col & 7))];
        acc3 = __builtin_amdgcn_mfma_f32_16x16x32_f16(af, wv[(20 + ks)*64 + lane], acc3, 0, 0, 0);
    }
    #pragma unroll
    for (int i = 0; i < 4; ++i) {
        int r = r0 + mt*16 + q*4 + i;
        out[(b*NIN + col)*N_ + r] = acc3[i];   // pred transposed: [B, n_out, N]
    }
}

// ---------------------------------------------------------------------------
extern "C" void kernel_launch(void* const* d_in, const int* in_sizes, int n_in,
                              void* d_out, int out_size, void* d_ws, size_t ws_size,
                              hipStream_t stream)
{
    const float* inp = (const float*)d_in[0];
    // d_in[1] = rel_rec, d_in[2] = rel_send: one-hot, decoded analytically, unused
    const float* rt  = (const float*)d_in[3];
    const float* W1  = (const float*)d_in[4];
    const float* b1  = (const float*)d_in[5];
    const float* W2  = (const float*)d_in[6];
    const float* b2  = (const float*)d_in[7];
    const float* Wo1 = (const float*)d_in[8];
    const float* bo1 = (const float*)d_in[9];
    const float* Wo2 = (const float*)d_in[10];
    const float* bo2 = (const float*)d_in[11];
    const float* Wo3 = (const float*)d_in[12];
    const float* bo3 = (const float*)d_in[13];

    // ws: Sh 2MB | Rh 2MB | w2h 32KB | wn 22KB | rtn 4MB | aggK 4MB (~12.3MB)
    _Float16* Sh   = (_Float16*)d_ws;
    _Float16* Rh   = Sh + (1u << 20);
    _Float16* w2h  = Rh + (1u << 20);
    _Float16* wn   = w2h + 16384;
    _Float16* rtn  = wn + 11264;
    float*    aggK = (float*)(rtn + (1u << 21));

    hipLaunchKernelGGL(prep, dim3(1644), dim3(256), 0, stream,
                       inp, W1, b1, W2, Wo1, Wo2, Wo3, rt, Sh, Rh, w2h, wn, rtn);
    hipLaunchKernelGGL(edge_mfma, dim3(512), dim3(512), 0, stream,
                       Sh, Rh, w2h, rtn, b2, aggK);
    hipLaunchKernelGGL(node_mfma, dim3(64), dim3(256), 0, stream,
                       aggK, inp, wn, bo1, bo2, bo3, (float*)d_out);
}

// Round 7
// 134.627 us; speedup vs baseline: 1.0665x; 1.0228x over previous
//
#include <hip/hip_runtime.h>
#include <stdint.h>

// Problem constants (fixed by reference)
#define B_  32
#define N_  128
#define NIN 16
#define K_  4
#define E_  (N_*(N_-1))   // 16256

typedef float    f4 __attribute__((ext_vector_type(4)));
typedef _Float16 h8 __attribute__((ext_vector_type(8)));   // 8 fp16 = 4 VGPRs
typedef _Float16 h4 __attribute__((ext_vector_type(4)));   // 4 fp16 = 2 VGPRs

// ---------------------------------------------------------------------------
// Prep (single launch, block ranges):
//   [0,1024):      S/R per-node layer-1 halves (fp16), 4 outputs/thread
//   [1024,1088):   W2 -> fp16 MFMA B-operand fragments (edge kernel)
//   [1088,1132):   Wo1/Wo2/Wo3 -> fp16 MFMA B-operand fragments (node kernel)
//   [1132,1644):   rel_types -> rtf[k][b][r][s] FP32, diagonal zeroed
//                  (sender-indexed: s = j + (j>=r)); coalesced float4 reads
// ---------------------------------------------------------------------------
__global__ __launch_bounds__(256) void prep(
    const float* __restrict__ inp, const float* __restrict__ W1,
    const float* __restrict__ b1,  const float* __restrict__ W2,
    const float* __restrict__ Wo1, const float* __restrict__ Wo2,
    const float* __restrict__ Wo3, const float* __restrict__ rt,
    _Float16* __restrict__ Sh, _Float16* __restrict__ Rh,
    _Float16* __restrict__ w2h, _Float16* __restrict__ wn,
    float* __restrict__ rtf)
{
    const int bid = blockIdx.x;
    const int tid = threadIdx.x;
    if (bid < 1024) {
        // 4 consecutive c per thread; S = x@W1[:16], R = x@W1[16:] + b1
        int gid = bid*256 + tid;            // c4:4 | n:7 | b:5 | k:2
        int c0 = (gid & 15)*4;
        int n  = (gid >> 4) & 127;
        int b  = (gid >> 11) & 31;
        int k  = gid >> 16;
        f4 s = {0.f,0.f,0.f,0.f};
        f4 r = *(const f4*)(b1 + k*64 + c0);
        const float* xp  = inp + (b*NIN)*N_ + n;          // inputs[b][f][n]
        const f4* w1s = (const f4*)(W1 + (k*32)*64 + c0);      // stride 16 f4
        const f4* w1r = (const f4*)(W1 + (k*32 + 16)*64 + c0);
        #pragma unroll
        for (int f = 0; f < 16; ++f) {
            float xv = xp[f*N_];
            s += xv * w1s[f*16];
            r += xv * w1r[f*16];
        }
        int base = ((k*B_ + b)*N_ + n)*64 + c0;
        h4 sh, rh;
        #pragma unroll
        for (int u = 0; u < 4; ++u) { sh[u] = (_Float16)s[u]; rh[u] = (_Float16)r[u]; }
        *(h4*)(Sh + base) = sh;
        *(h4*)(Rh + base) = rh;
    } else if (bid < 1088) {
        // edge B-frag: lane holds B[kk=q*8+i][n=nt*16+col]
        int t = (bid - 1024)*256 + tid;     // i:3 | lane:6 | nt:2 | ks:1 | k:2
        int i    = t & 7;
        int lane = (t >> 3) & 63;
        int nt   = (t >> 9) & 3;
        int ks   = (t >> 11) & 1;
        int k    = t >> 12;
        int c = ks*32 + (lane >> 4)*8 + i;
        int o = nt*16 + (lane & 15);
        w2h[t] = (_Float16)W2[(k*64 + c)*64 + o];
    } else if (bid < 1132) {
        // node-MLP B-frags (11264 = 44*256 exactly)
        int t = (bid - 1088)*256 + tid;     // j:3 | lane:6 | f:5
        int j    = t & 7;
        int lane = (t >> 3) & 63;
        int f    = t >> 9;                  // 0..21
        int col = lane & 15, q = lane >> 4, row = q*8 + j;
        float v;
        if (f < 12) {
            int ks = f >> 2, nt = f & 3, i = ks*32 + row;
            v = (i < 80) ? Wo1[i*64 + nt*16 + col] : 0.f;
        } else if (f < 20) {
            int g = f - 12, ks = g >> 2, nt = g & 3, i = ks*32 + row;
            v = Wo2[i*64 + nt*16 + col];
        } else {
            int ks = f - 20, i = ks*32 + row;
            v = Wo3[i*16 + col];
        }
        wn[t] = (_Float16)v;
    } else {
        // rtf[k][b][r][s]: sender-indexed edge weight (f32), 0 on diagonal.
        // thread <-> (b, r, jg); reads float4 over k (fully coalesced).
        int t = (bid - 1132)*256 + tid;     // jg:5 | r:7 | b:5
        int jg = t & 31;
        int r  = (t >> 5) & 127;
        int b  = t >> 12;
        const f4* rt4p = (const f4*)(rt + (size_t)(b*E_ + r*127)*4);
        #pragma unroll
        for (int u = 0; u < 4; ++u) {
            int j = jg*4 + u;
            if (j < 127) {
                f4 v = rt4p[j];
                int s = j + (j >= r ? 1 : 0);
                #pragma unroll
                for (int k = 0; k < 4; ++k)
                    rtf[(size_t)((k*B_ + b)*N_ + r)*N_ + s] = v[k];
            } else {
                #pragma unroll
                for (int k = 0; k < 4; ++k)      // zero the diagonal
                    rtf[(size_t)((k*B_ + b)*N_ + r)*N_ + r] = 0.f;
            }
        }
    }
}

// ---------------------------------------------------------------------------
// Edge MLP (fp16 MFMA) + receiver aggregation — REGISTER-RESIDENT A operand.
// Block = (k, b, eighth-of-receivers): 1024 blocks x 256 thr (4 waves).
// Wave = (s-half h, group p of 8 receivers). Per lane the A fragments are
// only rows mt*16+col, chunks q/4+q -> sf[4][2] = 32 VGPR, loaded from
// global ONCE. Inner loop: zero global loads, one broadcast ds_read_b128
// (rt weights), rest pure register math. Halves combine via LDS at end.
// ---------------------------------------------------------------------------
__global__ __launch_bounds__(256) void edge_mfma(
    const _Float16* __restrict__ Sh, const _Float16* __restrict__ Rh,
    const _Float16* __restrict__ w2h, const float* __restrict__ rtf,
    const float* __restrict__ b2, float* __restrict__ aggK)
{
    __shared__ _Float16 Rlh[16*64];        // 2 KB: R rows (fp16)
    __shared__ float    Rtf[16*128];       // 8 KB: rt rows (f32)
    __shared__ float    aggW[2][2][8][64]; // 8 KB: [p][h][rg][c]

    const int tid  = threadIdx.x;
    const int wave = tid >> 6;
    const int lane = tid & 63;
    const int col  = lane & 15;
    const int q    = lane >> 4;
    const int h    = wave & 1;          // sender half
    const int p    = wave >> 1;         // receiver group
    const int bid  = blockIdx.x;        // (k*32 + b)*8 + re
    const int re   = bid & 7;
    const int b    = (bid >> 3) & 31;
    const int k    = bid >> 8;
    const int kb   = k*B_ + b;
    const int r0   = re*16;

    // ---- stage R rows (fp16) + rt rows (f32) into LDS, coalesced ----
    if (tid < 128)
        *(h8*)(Rlh + tid*8) = *(const h8*)(Rh + ((size_t)kb*N_ + r0)*64 + tid*8);
    {
        const float* src = rtf + ((size_t)kb*N_ + r0)*N_;
        *(f4*)(Rtf + tid*4)        = *(const f4*)(src + tid*4);
        *(f4*)(Rtf + 1024 + tid*4) = *(const f4*)(src + 1024 + tid*4);
    }

    // ---- A-operand S fragments: direct global -> VGPR (32 regs) ----
    h8 sf[4][2];
    const _Float16* Sg = Sh + ((size_t)kb*N_ + h*64)*64;
    #pragma unroll
    for (int mt = 0; mt < 4; ++mt) {
        sf[mt][0] = *(const h8*)(Sg + (mt*16 + col)*64 + q*8);
        sf[mt][1] = *(const h8*)(Sg + (mt*16 + col)*64 + (4 + q)*8);
    }

    // W2 B-operand fragments (global, L2-broadcast)
    const h8* w2v = (const h8*)w2h;
    h8 w2f[2][4];
    #pragma unroll
    for (int ks = 0; ks < 2; ++ks)
        #pragma unroll
        for (int nt = 0; nt < 4; ++nt)
            w2f[ks][nt] = w2v[((k*2 + ks)*4 + nt)*64 + lane];

    // b2 folded into accumulator init (C col = lane&15 for all 4 regs)
    f4 b2i[4];
    #pragma unroll
    for (int nt = 0; nt < 4; ++nt) {
        float v = b2[k*64 + nt*16 + col];
        b2i[nt][0] = v; b2i[nt][1] = v; b2i[nt][2] = v; b2i[nt][3] = v;
    }

    __syncthreads();

    const h8 zero8 = {0,0,0,0,0,0,0,0};
    const f4 zero4 = {0.f,0.f,0.f,0.f};

    #pragma unroll 1
    for (int rg = 0; rg < 8; ++rg) {
        const int rl = p*8 + rg;        // receiver-local index
        h8 rf0 = *(const h8*)(Rlh + rl*64 + q*8);
        h8 rf1 = *(const h8*)(Rlh + rl*64 + (4 + q)*8);

        f4 vacc[4] = {zero4, zero4, zero4, zero4};
        #pragma unroll
        for (int mt = 0; mt < 4; ++mt) {
            // rt weights for rows q*4..q*4+3 (quad-broadcast b128, f32)
            f4 rt4 = *(const f4*)(Rtf + rl*128 + h*64 + mt*16 + q*4);
            // h1 = relu(S[sender] + R[recv]), packed fp16, register-resident
            h8 a0 = __builtin_elementwise_max(sf[mt][0] + rf0, zero8);
            h8 a1 = __builtin_elementwise_max(sf[mt][1] + rf1, zero8);

            #pragma unroll
            for (int nt = 0; nt < 4; ++nt) {
                f4 acc = __builtin_amdgcn_mfma_f32_16x16x32_f16(a0, w2f[0][nt], b2i[nt], 0, 0, 0);
                acc     = __builtin_amdgcn_mfma_f32_16x16x32_f16(a1, w2f[1][nt], acc,    0, 0, 0);
                // C/D: col = lane&15, row = q*4 + reg
                f4 m = __builtin_elementwise_max(acc, zero4);
                vacc[nt] += rt4 * m;    // packed f32 fma
            }
        }
        // horizontal sum over the 4 rows, then cross-quad reduce
        #pragma unroll
        for (int nt = 0; nt < 4; ++nt) {
            float v = vacc[nt][0] + vacc[nt][1] + vacc[nt][2] + vacc[nt][3];
            v += __shfl_xor(v, 16, 64);
            v += __shfl_xor(v, 32, 64);
            if (lane < 16) aggW[p][h][rg][nt*16 + lane] = v;
        }
    }
    __syncthreads();

    // combine the two sender-halves, write aggK[k][b][r][c]
    {
        int rl = tid >> 4, c4 = tid & 15;
        f4 v = *(const f4*)(&aggW[rl >> 3][0][rl & 7][c4*4])
             + *(const f4*)(&aggW[rl >> 3][1][rl & 7][c4*4]);
        *(f4*)(aggK + ((size_t)kb*N_ + r0 + rl)*64 + c4*4) = v;
    }
}

// ---------------------------------------------------------------------------
// Node MLP via MFMA. Block = (b, half-of-r): 64 blocks x 256 thr (4 waves).
// aug[64 nodes][96 pad] fp16 in LDS (XOR-swizzled); wave mt owns nodes
// mt*16..+15; 3 GEMM layers, inter-layer h in wave-private LDS rows.
// ---------------------------------------------------------------------------
__global__ __launch_bounds__(256) void node_mfma(
    const float* __restrict__ aggK, const float* __restrict__ inp,
    const _Float16* __restrict__ wn,
    const float* __restrict__ bo1, const float* __restrict__ bo2,
    const float* __restrict__ bo3, float* __restrict__ out)
{
    __shared__ _Float16 augH[64*128];   // 16 KB
    __shared__ _Float16 h12[64*64];     // 8 KB

    const int tid = threadIdx.x;
    const int b   = blockIdx.x >> 1;
    const int r0  = (blockIdx.x & 1)*64;

    // ---- build aug[node][96]: [x(16) | sum_k aggK (64) | zeros(16)] ----
    {
        const int nl = tid >> 2, c4 = tid & 3;      // node-local, quarter
        const int r  = r0 + nl;
        float xv[4];
        #pragma unroll
        for (int u = 0; u < 4; ++u)
            xv[u] = inp[(b*NIN + c4*4 + u)*N_ + r];
        f4 av[4];
        #pragma unroll
        for (int w = 0; w < 4; ++w) {
            int c = w*16 + c4*4;
            f4 a = {0.f,0.f,0.f,0.f};
            #pragma unroll
            for (int k = 0; k < 4; ++k)
                a += *(const f4*)(aggK + (((size_t)k*B_ + b)*N_ + r)*64 + c);
            av[w] = a;
        }
        #pragma unroll
        for (int u = 0; u < 4; ++u) {
            int i = c4*4 + u;
            augH[nl*128 + (((i>>3) ^ (nl&15))<<3) + (i&7)] = (_Float16)xv[u];
        }
        #pragma unroll
        for (int w = 0; w < 4; ++w)
            #pragma unroll
            for (int u = 0; u < 4; ++u) {
                int i = 16 + w*16 + c4*4 + u;
                augH[nl*128 + (((i>>3) ^ (nl&15))<<3) + (i&7)] = (_Float16)av[w][u];
            }
        if (c4 < 2)
            #pragma unroll
            for (int u = 0; u < 8; ++u) {
                int i = 80 + c4*8 + u;
                augH[nl*128 + (((i>>3) ^ (nl&15))<<3) + (i&7)] = (_Float16)0.f;
            }
    }
    __syncthreads();

    // ---- GEMM chain: wave mt -> nodes mt*16..+15 ----
    const int mt  = tid >> 6, lane = tid & 63;
    const int col = lane & 15, q = lane >> 4;
    const h8* wv   = (const h8*)wn;
    const h8* augV = (const h8*)augH;
    const h8* hv   = (const h8*)h12;
    const int nl   = mt*16 + col;       // A row (node); nl&15 == col

    // layer 1: [96] -> [64], relu
    f4 acc[4];
    #pragma unroll
    for (int nt = 0; nt < 4; ++nt) {
        float v = bo1[nt*16 + col];
        acc[nt][0] = v; acc[nt][1] = v; acc[nt][2] = v; acc[nt][3] = v;
    }
    #pragma unroll
    for (int ks = 0; ks < 3; ++ks) {
        h8 af = augV[nl*16 + ((ks*4 + q) ^ col)];
        #pragma unroll
        for (int nt = 0; nt < 4; ++nt)
            acc[nt] = __builtin_amdgcn_mfma_f32_16x16x32_f16(af, wv[(ks*4 + nt)*64 + lane], acc[nt], 0, 0, 0);
    }
    #pragma unroll
    for (int nt = 0; nt < 4; ++nt)
        #pragma unroll
        for (int i = 0; i < 4; ++i) {
            int n2 = mt*16 + q*4 + i, o = nt*16 + col;
            h12[n2*64 + (((o>>3) ^ (n2&7))<<3) + (o&7)] = (_Float16)fmaxf(acc[nt][i], 0.f);
        }

    // layer 2: [64] -> [64], relu (wave-private rows; in-order LDS)
    f4 acc2[4];
    #pragma unroll
    for (int nt = 0; nt < 4; ++nt) {
        float v = bo2[nt*16 + col];
        acc2[nt][0] = v; acc2[nt][1] = v; acc2[nt][2] = v; acc2[nt][3] = v;
    }
    #pragma unroll
    for (int ks = 0; ks < 2; ++ks) {
        h8 af = hv[nl*8 + ((ks*4 + q) ^ (col & 7))];
        #pragma unroll
        for (int nt = 0; nt < 4; ++nt)
            acc2[nt] = __builtin_amdgcn_mfma_f32_16x16x32_f16(af, wv[(12 + ks*4 + nt)*64 + lane], acc2[nt], 0, 0, 0);
    }
    #pragma unroll
    for (int nt = 0; nt < 4; ++nt)
        #pragma unroll
        for (int i = 0; i < 4; ++i) {
            int n2 = mt*16 + q*4 + i, o = nt*16 + col;
            h12[n2*64 + (((o>>3) ^ (n2&7))<<3) + (o&7)] = (_Float16)fmaxf(acc2[nt][i], 0.f);
        }

    // layer 3: [64] -> [16], no relu
    f4 acc3;
    {
        float v = bo3[col];
        acc3[0] = v; acc3[1] = v; acc3[2] = v; acc3[3] = v;
    }
    #pragma unroll
    for (int ks = 0; ks < 2; ++ks) {
        h8 af = hv[nl*8 + ((ks*4 + q) ^ (col & 7))];
        acc3 = __builtin_amdgcn_mfma_f32_16x16x32_f16(af, wv[(20 + ks)*64 + lane], acc3, 0, 0, 0);
    }
    #pragma unroll
    for (int i = 0; i < 4; ++i) {
        int r = r0 + mt*16 + q*4 + i;
        out[(b*NIN + col)*N_ + r] = acc3[i];   // pred transposed: [B, n_out, N]
    }
}

// ---------------------------------------------------------------------------
extern "C" void kernel_launch(void* const* d_in, const int* in_sizes, int n_in,
                              void* d_out, int out_size, void* d_ws, size_t ws_size,
                              hipStream_t stream)
{
    const float* inp = (const float*)d_in[0];
    // d_in[1] = rel_rec, d_in[2] = rel_send: one-hot, decoded analytically, unused
    const float* rt  = (const float*)d_in[3];
    const float* W1  = (const float*)d_in[4];
    const float* b1  = (const float*)d_in[5];
    const float* W2  = (const float*)d_in[6];
    const float* b2  = (const float*)d_in[7];
    const float* Wo1 = (const float*)d_in[8];
    const float* bo1 = (const float*)d_in[9];
    const float* Wo2 = (const float*)d_in[10];
    const float* bo2 = (const float*)d_in[11];
    const float* Wo3 = (const float*)d_in[12];
    const float* bo3 = (const float*)d_in[13];

    // ws: Sh 2MB | Rh 2MB | w2h 32KB | wn 22KB | rtf 8MB f32 | aggK 4MB (~16.3MB)
    _Float16* Sh   = (_Float16*)d_ws;
    _Float16* Rh   = Sh + (1u << 20);
    _Float16* w2h  = Rh + (1u << 20);
    _Float16* wn   = w2h + 16384;
    float*    rtf  = (float*)(wn + 11264);
    float*    aggK = rtf + (1u << 21);

    hipLaunchKernelGGL(prep, dim3(1644), dim3(256), 0, stream,
                       inp, W1, b1, W2, Wo1, Wo2, Wo3, rt, Sh, Rh, w2h, wn, rtf);
    hipLaunchKernelGGL(edge_mfma, dim3(1024), dim3(256), 0, stream,
                       Sh, Rh, w2h, rtf, b2, aggK);
    hipLaunchKernelGGL(node_mfma, dim3(64), dim3(256), 0, stream,
                       aggK, inp, wn, bo1, bo2, bo3, (float*)d_out);
}